// Round 3
// baseline (1888.779 us; speedup 1.0000x reference)
//
#include <hip/hip_runtime.h>

typedef unsigned int u32;
typedef unsigned short u16;

typedef _Float16 f16x8 __attribute__((ext_vector_type(8)));
typedef float    f32x4 __attribute__((ext_vector_type(4)));

constexpr int NN = 100000;   // nodes
constexpr int NE = 1600000;  // edges
constexpr int NG = 256;      // graphs
constexpr int DH = 128;      // hidden dim
constexpr int NL = 4;        // GIN layers
constexpr int NTILES = NN / 16;  // 6250

// All fp16 node buffers use column-sliced layout: hs[slice=8][NN][16] halfs.
// A 16-col slice is 3.2 MB -> fits one XCD's 4 MiB L2; k_agg pins slice s to
// XCD s via blockIdx%8 so the random src-row gathers become L2 hits.

// d_out layout (fp32 elements)
constexpr long long OFF_EMB  = 0;                       // 5*NN*128
constexpr long long OFF_PS   = 64000000LL;              // 256*128
constexpr long long OFF_L1   = OFF_PS  + (long long)NG*DH;
constexpr long long OFF_L1D  = OFF_L1  + (long long)NG*DH;
constexpr long long OFF_L2   = OFF_L1D + (long long)NG*DH;
constexpr long long OFF_SOFT = OFF_L2  + (long long)NG*8;

__device__ __forceinline__ u16 f2h(float f) {
    union { _Float16 h; u16 s; } c; c.h = (_Float16)f; return c.s;
}
__device__ __forceinline__ float h2f(u16 s) {
    union { u16 s; _Float16 h; } c; c.s = s; return (float)c.h;
}

union U16x8 { uint4 u; f16x8 h; u16 s[8]; };

// ---------------- CSR build ----------------
__global__ __launch_bounds__(256) void k_hist(const int* __restrict__ ei, int* __restrict__ cnt) {
    int e = blockIdx.x * 256 + threadIdx.x;
    if (e < NE) atomicAdd(&cnt[ei[e]], 1);
}

__global__ __launch_bounds__(256) void k_scan1(const int* __restrict__ cnt,
                                               int* __restrict__ rp, int* __restrict__ bsum) {
    __shared__ int sd[256];
    int t = threadIdx.x;
    int base = blockIdx.x * 1024 + t * 4;
    int v0 = (base + 0 < NN) ? cnt[base + 0] : 0;
    int v1 = (base + 1 < NN) ? cnt[base + 1] : 0;
    int v2 = (base + 2 < NN) ? cnt[base + 2] : 0;
    int v3 = (base + 3 < NN) ? cnt[base + 3] : 0;
    int s = v0 + v1 + v2 + v3;
    sd[t] = s; __syncthreads();
    for (int off = 1; off < 256; off <<= 1) {
        int x = (t >= off) ? sd[t - off] : 0;
        __syncthreads();
        sd[t] += x;
        __syncthreads();
    }
    int e = sd[t] - s;
    if (base + 0 < NN) rp[base + 0] = e; e += v0;
    if (base + 1 < NN) rp[base + 1] = e; e += v1;
    if (base + 2 < NN) rp[base + 2] = e; e += v2;
    if (base + 3 < NN) rp[base + 3] = e;
    if (t == 255) bsum[blockIdx.x] = sd[255];
}

__global__ void k_scan2(int* __restrict__ bsum, int nb) {
    __shared__ int sd[128];
    int t = threadIdx.x;
    int v = (t < nb) ? bsum[t] : 0;
    sd[t] = v; __syncthreads();
    for (int off = 1; off < 128; off <<= 1) {
        int x = (t >= off) ? sd[t - off] : 0;
        __syncthreads();
        sd[t] += x;
        __syncthreads();
    }
    if (t < nb) bsum[t] = sd[t] - v;
}

__global__ __launch_bounds__(256) void k_scan3(int* __restrict__ rp, const int* __restrict__ bsum) {
    int t = threadIdx.x;
    int base = blockIdx.x * 1024 + t * 4;
    int add = bsum[blockIdx.x];
    #pragma unroll
    for (int j = 0; j < 4; ++j)
        if (base + j < NN) rp[base + j] += add;
    if (blockIdx.x == 0 && t == 0) rp[NN] = NE;
}

// scatter (src, w) interleaved: one 8B random store per edge.
__global__ __launch_bounds__(256) void k_scatter(const int* __restrict__ ei,
                                                 const float* __restrict__ mask,
                                                 const int* __restrict__ rp,
                                                 int* __restrict__ cur,
                                                 int2* __restrict__ ew) {
    int e = blockIdx.x * 256 + threadIdx.x;
    if (e >= NE) return;
    int d = ei[e];
    int pos = rp[d] + atomicAdd(&cur[d], 1);
    ew[pos] = make_int2(ei[NE + e], __float_as_int(mask[e]));
}

// ---------------- aggregation: pooled = agg + (1+eps)*h, sliced fp16 ----------------
// blockIdx&7 = slice = XCD (round-robin dispatch); block's 4 waves handle 4
// consecutive nodes for that slice. Per 8-edge batch: lane L handles edge
// (b + L>>3), col-pair L&7 -> one 8B meta load (broadcast within 8-lane
// groups, nontemporal) + one 4B gather from the L2-resident 3.2MB slice.
// Final 3-round shfl_xor tree reduces the 8 edge-groups.
__global__ __launch_bounds__(256) void k_agg(const u16* __restrict__ h,
                                             u16* __restrict__ pooled,
                                             const int* __restrict__ rp,
                                             const int2* __restrict__ ew,
                                             const float* __restrict__ eps, int layer) {
    const int lane = threadIdx.x & 63;
    const int wid  = threadIdx.x >> 6;
    const int s    = blockIdx.x & 7;
    const int node = (blockIdx.x >> 3) * 4 + wid;
    const int colpair = lane & 7, esub = lane >> 3;
    const u32* hs = (const u32*)h + (size_t)s * NN * 8;
    int e0 = rp[node], e1 = rp[node + 1];
    float a0 = 0.f, a1 = 0.f;
    #pragma unroll 4
    for (int b = e0; b < e1; b += 8) {
        int idx = b + esub;
        int cidx = idx < e1 ? idx : e1 - 1;
        long long ll = __builtin_nontemporal_load((const long long*)(ew + cidx));
        int src = (int)ll;
        float w = (idx < e1) ? __int_as_float((int)(ll >> 32)) : 0.f;
        u32 v = hs[(size_t)src * 8 + colpair];
        a0 += w * h2f((u16)(v & 0xffff));
        a1 += w * h2f((u16)(v >> 16));
    }
    a0 += __shfl_xor(a0, 8);  a1 += __shfl_xor(a1, 8);
    a0 += __shfl_xor(a0, 16); a1 += __shfl_xor(a1, 16);
    a0 += __shfl_xor(a0, 32); a1 += __shfl_xor(a1, 32);
    if (lane < 8) {
        float ep = 1.f + eps[layer];
        u32 v = hs[(size_t)node * 8 + colpair];
        a0 += ep * h2f((u16)(v & 0xffff));
        a1 += ep * h2f((u16)(v >> 16));
        u32 o = (u32)f2h(a0) | ((u32)f2h(a1) << 16);
        __builtin_nontemporal_store(o, (u32*)pooled + (size_t)s * NN * 8 + (size_t)node * 8 + colpair);
    }
}

// ---- shared W-fragment loader: B[k][n] = W[n][k]; lane holds n=lane&15, k=q*8+j;
// hi/lo split recovers fp32 W precision through fp16 MFMA.
__device__ __forceinline__ void load_wfrags(const float* __restrict__ W,
                                            const float* __restrict__ b,
                                            int sub, int m, int q,
                                            f16x8 (&bhi)[2][4], f16x8 (&blo)[2][4],
                                            float (&bs)[2]) {
    #pragma unroll
    for (int t = 0; t < 2; ++t) {
        int n = sub * 32 + t * 16 + m;
        const float* wr = W + (size_t)n * 128 + q * 8;
        bs[t] = b[n];
        #pragma unroll
        for (int kb = 0; kb < 4; ++kb) {
            float4 f0 = *(const float4*)(wr + kb * 32);
            float4 f1 = *(const float4*)(wr + kb * 32 + 4);
            float f[8] = {f0.x, f0.y, f0.z, f0.w, f1.x, f1.y, f1.z, f1.w};
            f16x8 hi, lo;
            #pragma unroll
            for (int j = 0; j < 8; ++j) {
                _Float16 h = (_Float16)f[j];
                hi[j] = h;
                lo[j] = (_Float16)(f[j] - (float)h);
            }
            bhi[t][kb] = hi;
            blo[t][kb] = lo;
        }
    }
}

// A-fragment load from sliced fp16 layout: 16B at (row, col block of 8),
// col = q*8 + kb*32 -> slice = col>>4, within-slice offset = col&15.
__device__ __forceinline__ void load_a_sliced(const u16* __restrict__ A, int row, int q,
                                              f16x8 (&af)[4]) {
    #pragma unroll
    for (int kb = 0; kb < 4; ++kb) {
        int col = q * 8 + kb * 32;
        const uint4* ap = (const uint4*)(A + ((size_t)(col >> 4) * NN + row) * 16 + (col & 15));
        U16x8 u; u.u = *ap;
        af[kb] = u.h;
    }
}

// ---------------- GEMM: out[M,128] = A[M,128] @ W^T + b (first layer, fp32 A) ----
__global__ __launch_bounds__(256) void k_gemm(const float* __restrict__ Af32,
                                              const float* __restrict__ W,
                                              const float* __restrict__ bias,
                                              u16* __restrict__ outh,
                                              float* __restrict__ outf,
                                              int relu, int M) {
    __shared__ float stage[4][16 * 36];
    float* st = stage[threadIdx.x >> 6];
    const int lane = threadIdx.x & 63;
    const int wid = (blockIdx.x * 256 + threadIdx.x) >> 6;
    const int nwaves = (gridDim.x * 256) >> 6;
    const int m = lane & 15, q = lane >> 4;
    const int pair = wid & 3;          // cols [pair*32, pair*32+32)
    const int tile0 = wid >> 2;
    const int tstride = nwaves >> 2;

    f16x8 bhi[2][4], blo[2][4];
    float bs[2];
    load_wfrags(W, bias, pair, m, q, bhi, blo, bs);

    const int rdrow = lane >> 2, rdcg = lane & 3;   // epilogue readback mapping
    const int ntiles = M / 16;
    for (int tile = tile0; tile < ntiles; tile += tstride) {
        int row0 = tile * 16;
        f16x8 af[4];
        const float* ap = Af32 + (size_t)(row0 + m) * 128 + q * 8;
        #pragma unroll
        for (int kb = 0; kb < 4; ++kb) {
            f32x4 f0 = __builtin_nontemporal_load((const f32x4*)(ap + kb * 32));
            f32x4 f1 = __builtin_nontemporal_load((const f32x4*)(ap + kb * 32 + 4));
            f16x8 hh;
            hh[0] = (_Float16)f0[0]; hh[1] = (_Float16)f0[1];
            hh[2] = (_Float16)f0[2]; hh[3] = (_Float16)f0[3];
            hh[4] = (_Float16)f1[0]; hh[5] = (_Float16)f1[1];
            hh[6] = (_Float16)f1[2]; hh[7] = (_Float16)f1[3];
            af[kb] = hh;
        }
        f32x4 acc[2] = {{0.f, 0.f, 0.f, 0.f}, {0.f, 0.f, 0.f, 0.f}};
        #pragma unroll
        for (int t = 0; t < 2; ++t)
            #pragma unroll
            for (int kb = 0; kb < 4; ++kb) {
                acc[t] = __builtin_amdgcn_mfma_f32_16x16x32_f16(af[kb], bhi[t][kb], acc[t], 0, 0, 0);
                acc[t] = __builtin_amdgcn_mfma_f32_16x16x32_f16(af[kb], blo[t][kb], acc[t], 0, 0, 0);
            }
        // stage to LDS: C/D layout col=lane&15, row=q*4+r (m89/m91)
        #pragma unroll
        for (int t = 0; t < 2; ++t)
            #pragma unroll
            for (int r = 0; r < 4; ++r) {
                float v = acc[t][r] + bs[t];
                if (relu) v = fmaxf(v, 0.f);
                st[(q * 4 + r) * 36 + t * 16 + m] = v;
            }
        // coalesced readback + stores (wave-private region; lgkmcnt ordering)
        f32x4 v0 = *(const f32x4*)&st[rdrow * 36 + rdcg * 8];
        f32x4 v1 = *(const f32x4*)&st[rdrow * 36 + rdcg * 8 + 4];
        int colbase = pair * 32 + rdcg * 8;
        size_t gbase = (size_t)(row0 + rdrow) * 128 + colbase;
        size_t hbase = ((size_t)(colbase >> 4) * NN + (row0 + rdrow)) * 16 + (colbase & 15);
        U16x8 p;
        p.s[0] = f2h(v0[0]); p.s[1] = f2h(v0[1]); p.s[2] = f2h(v0[2]); p.s[3] = f2h(v0[3]);
        p.s[4] = f2h(v1[0]); p.s[5] = f2h(v1[1]); p.s[6] = f2h(v1[2]); p.s[7] = f2h(v1[3]);
        *(uint4*)(outh + hbase) = p.u;
        if (outf) {
            __builtin_nontemporal_store(v0, (f32x4*)(outf + gbase));
            __builtin_nontemporal_store(v1, (f32x4*)(outf + gbase + 4));
        }
    }
}

// ---------------- fused SLP: out = relu(relu(A@W0^T+b0)@W1^T+b1) ----------------
// 8 waves / block; producers (0-3) GEMM1 -> LDS fp16 double-buffer; consumers
// (4-7) GEMM2 -> sliced fp16 + nt fp32 stores. A reads / fp16 writes use the
// sliced layout (addressing only; every access stays 16B within one slice).
__global__ __launch_bounds__(512) void k_slp(const u16* __restrict__ A,
                                             const float* __restrict__ W0,
                                             const float* __restrict__ b0,
                                             const float* __restrict__ W1,
                                             const float* __restrict__ b1,
                                             u16* __restrict__ outh,
                                             float* __restrict__ outf) {
    __shared__ u16 inter[2][16 * 136];      // 136-half row stride: 16B-aligned rows
    __shared__ float stage[4][16 * 36];
    const int lane = threadIdx.x & 63;
    const int w8 = threadIdx.x >> 6;        // 0..7
    const int m = lane & 15, q = lane >> 4;
    const int sub = w8 & 3;
    const int G = gridDim.x;
    const int nt = (NTILES - (int)blockIdx.x + G - 1) / G;   // G <= NTILES

    if (w8 < 4) {
        // -------- producer: inter = relu(A @ W0^T + b0), fp16 --------
        f16x8 bhi[2][4], blo[2][4];
        float bs[2];
        load_wfrags(W0, b0, sub, m, q, bhi, blo, bs);

        f16x8 afc[4], afn[4];
        load_a_sliced(A, (int)blockIdx.x * 16 + m, q, afc);   // prologue, tile 0
        for (int i = 0; i < nt; ++i) {
            int tn = (int)blockIdx.x + (i + 1) * G;
            if (tn < NTILES)    // prefetch next tile's A before MFMA on current
                load_a_sliced(A, tn * 16 + m, q, afn);
            f32x4 acc[2] = {{0.f, 0.f, 0.f, 0.f}, {0.f, 0.f, 0.f, 0.f}};
            #pragma unroll
            for (int t = 0; t < 2; ++t)
                #pragma unroll
                for (int kb = 0; kb < 4; ++kb) {
                    acc[t] = __builtin_amdgcn_mfma_f32_16x16x32_f16(afc[kb], bhi[t][kb], acc[t], 0, 0, 0);
                    acc[t] = __builtin_amdgcn_mfma_f32_16x16x32_f16(afc[kb], blo[t][kb], acc[t], 0, 0, 0);
                }
            u16* ib = inter[i & 1];
            #pragma unroll
            for (int t = 0; t < 2; ++t)
                #pragma unroll
                for (int r = 0; r < 4; ++r) {
                    float v = fmaxf(acc[t][r] + bs[t], 0.f);
                    // C/D layout: row=q*4+r, col=sub*32+t*16+m
                    ib[(q * 4 + r) * 136 + sub * 32 + t * 16 + m] = f2h(v);
                }
            __syncthreads();
            #pragma unroll
            for (int kb = 0; kb < 4; ++kb) afc[kb] = afn[kb];
        }
        __syncthreads();   // matches consumer's final in-loop barrier
    } else {
        // -------- consumer: out = relu(inter @ W1^T + b1) --------
        f16x8 bhi[2][4], blo[2][4];
        float bs[2];
        load_wfrags(W1, b1, sub, m, q, bhi, blo, bs);
        float* st = stage[sub];
        const int rdrow = lane >> 2, rdcg = lane & 3;

        __syncthreads();   // matches producer's i=0 barrier: tile 0 now visible
        for (int i = 0; i < nt; ++i) {
            int tile = (int)blockIdx.x + i * G;
            const u16* ib = inter[i & 1];
            f16x8 af[4];
            #pragma unroll
            for (int kb = 0; kb < 4; ++kb)   // A row = lane&15, k = q*8 + kb*32 + j
                af[kb] = *(const f16x8*)&ib[m * 136 + q * 8 + kb * 32];
            f32x4 acc[2] = {{0.f, 0.f, 0.f, 0.f}, {0.f, 0.f, 0.f, 0.f}};
            #pragma unroll
            for (int t = 0; t < 2; ++t)
                #pragma unroll
                for (int kb = 0; kb < 4; ++kb) {
                    acc[t] = __builtin_amdgcn_mfma_f32_16x16x32_f16(af[kb], bhi[t][kb], acc[t], 0, 0, 0);
                    acc[t] = __builtin_amdgcn_mfma_f32_16x16x32_f16(af[kb], blo[t][kb], acc[t], 0, 0, 0);
                }
            #pragma unroll
            for (int t = 0; t < 2; ++t)
                #pragma unroll
                for (int r = 0; r < 4; ++r) {
                    float v = fmaxf(acc[t][r] + bs[t], 0.f);
                    st[(q * 4 + r) * 36 + t * 16 + m] = v;
                }
            f32x4 v0 = *(const f32x4*)&st[rdrow * 36 + rdcg * 8];
            f32x4 v1 = *(const f32x4*)&st[rdrow * 36 + rdcg * 8 + 4];
            int colbase = sub * 32 + rdcg * 8;
            size_t gbase = (size_t)(tile * 16 + rdrow) * 128 + colbase;
            size_t hbase = ((size_t)(colbase >> 4) * NN + (tile * 16 + rdrow)) * 16 + (colbase & 15);
            U16x8 p;
            p.s[0] = f2h(v0[0]); p.s[1] = f2h(v0[1]); p.s[2] = f2h(v0[2]); p.s[3] = f2h(v0[3]);
            p.s[4] = f2h(v1[0]); p.s[5] = f2h(v1[1]); p.s[6] = f2h(v1[2]); p.s[7] = f2h(v1[3]);
            *(uint4*)(outh + hbase) = p.u;
            __builtin_nontemporal_store(v0, (f32x4*)(outf + gbase));
            __builtin_nontemporal_store(v1, (f32x4*)(outf + gbase + 4));
            __syncthreads();
        }
    }
}

// ---------------- graph pooling from sliced fp16 embeds ----------------
__device__ __forceinline__ int lbound(const int* b, int n, int v) {
    int lo = 0, hi = n;
    while (lo < hi) { int mid = (lo + hi) >> 1; if (b[mid] < v) lo = mid + 1; else hi = mid; }
    return lo;
}

// lane = nsub(3b) x colpair(3b): 8 consecutive nodes x 8 u32 = 256B coalesced
// per load; slices iterated serially; 3-round shfl_xor tree per slice.
__global__ __launch_bounds__(128) void k_pool_partial(const u16* __restrict__ embH,
                                                      const int* __restrict__ batch,
                                                      float* __restrict__ ps_tmp) {
    int g = blockIdx.x >> 3, s8 = blockIdx.x & 7;
    int w = threadIdx.x >> 6, lane = threadIdx.x & 63;
    int st = s8 * 2 + w;               // 16 node stripes
    int nsub = lane >> 3, colpair = lane & 7;
    int lo = lbound(batch, NN, g);
    int hi = lbound(batch, NN, g + 1);
    const u32* h32 = (const u32*)embH;
    #pragma unroll
    for (int s = 0; s < 8; ++s) {
        float a0 = 0.f, a1 = 0.f;
        for (int n0 = lo + st * 8; n0 < hi; n0 += 128) {
            int n = n0 + nsub;
            if (n < hi) {
                #pragma unroll
                for (int e = 0; e < 5; ++e) {
                    u32 v = h32[((size_t)(e * 8 + s) * NN + n) * 8 + colpair];
                    a0 += h2f((u16)(v & 0xffff));
                    a1 += h2f((u16)(v >> 16));
                }
            }
        }
        a0 += __shfl_xor(a0, 8);  a1 += __shfl_xor(a1, 8);
        a0 += __shfl_xor(a0, 16); a1 += __shfl_xor(a1, 16);
        a0 += __shfl_xor(a0, 32); a1 += __shfl_xor(a1, 32);
        if (lane < 8) {
            atomicAdd(&ps_tmp[g * 128 + s * 16 + colpair * 2], a0);
            atomicAdd(&ps_tmp[g * 128 + s * 16 + colpair * 2 + 1], a1);
        }
    }
}

// ---------------- head: pooled_sum -> lin1 -> lin2 -> softmax ----------------
__global__ __launch_bounds__(128) void k_final(const float* __restrict__ ps_tmp,
                                               const float* __restrict__ W1, const float* __restrict__ b1,
                                               const float* __restrict__ W2, const float* __restrict__ b2,
                                               float* __restrict__ out) {
    int g = blockIdx.x, t = threadIdx.x;
    __shared__ float ps[128], l1[128], l2[8];
    float v = ps_tmp[g * 128 + t];
    ps[t] = v;
    out[OFF_PS + (size_t)g * 128 + t] = v;
    __syncthreads();
    float a = b1[t];
    #pragma unroll 8
    for (int k = 0; k < 128; ++k) a += ps[k] * W1[t * 128 + k];
    a = fmaxf(a, 0.f);
    l1[t] = a;
    out[OFF_L1  + (size_t)g * 128 + t] = a;
    out[OFF_L1D + (size_t)g * 128 + t] = a;
    __syncthreads();
    if (t < 8) {
        float a2 = b2[t];
        #pragma unroll 8
        for (int k = 0; k < 128; ++k) a2 += l1[k] * W2[t * 128 + k];
        l2[t] = a2;
        out[OFF_L2 + (size_t)g * 8 + t] = a2;
    }
    __syncthreads();
    if (t == 0) {
        float mx = l2[0];
        for (int j = 1; j < 8; ++j) mx = fmaxf(mx, l2[j]);
        float e[8], s = 0.f;
        for (int j = 0; j < 8; ++j) { e[j] = __expf(l2[j] - mx); s += e[j]; }
        float inv = 1.f / s;
        for (int j = 0; j < 8; ++j) out[OFF_SOFT + (size_t)g * 8 + j] = e[j] * inv;
    }
}

extern "C" void kernel_launch(void* const* d_in, const int* in_sizes, int n_in,
                              void* d_out, int out_size, void* d_ws, size_t ws_size,
                              hipStream_t stream) {
    const float* x       = (const float*)d_in[0];
    const int*   ei      = (const int*)d_in[1];
    const float* emask   = (const float*)d_in[2];
    const int*   batch   = (const int*)d_in[3];
    const float* eps     = (const float*)d_in[4];
    const float* W_first = (const float*)d_in[5];
    const float* b_first = (const float*)d_in[6];
    const float* gin_W   = (const float*)d_in[7];
    const float* gin_b   = (const float*)d_in[8];
    const float* W1      = (const float*)d_in[9];
    const float* b1      = (const float*)d_in[10];
    const float* W2      = (const float*)d_in[11];
    const float* b2      = (const float*)d_in[12];
    float* out = (float*)d_out;

    char* ws = (char*)d_ws;
    const size_t HB = (size_t)NN * 128 * 2;       // 25.6 MB per fp16 node buffer
    u16* embH = (u16*)(ws);                       // 5 contiguous embed buffers (sliced)
    size_t o = 5 * HB;
    u16* bufP = (u16*)(ws + o); o += HB;          // agg output (sliced)
    int* cnt  = (int*)(ws + o); o += 400000;
    int* cur  = (int*)(ws + o); o += 400000;
    float* ps_tmp = (float*)(ws + o); o += (size_t)NG * DH * 4;
    int* rp   = (int*)(ws + o); o += 400064;      // NN+1 ints, padded
    int* bsum = (int*)(ws + o); o += 512;
    int2* ew  = (int2*)(ws + o); o += (size_t)NE * 8;  // interleaved (src, w)

    // one memset covers cnt + cur + ps_tmp (adjacent)
    hipMemsetAsync(cnt, 0, 400000 + 400000 + (size_t)NG * DH * 4, stream);

    // CSR build
    k_hist<<<NE / 256, 256, 0, stream>>>(ei, cnt);
    k_scan1<<<98, 256, 0, stream>>>(cnt, rp, bsum);
    k_scan2<<<1, 128, 0, stream>>>(bsum, 98);
    k_scan3<<<98, 256, 0, stream>>>(rp, bsum);
    k_scatter<<<NE / 256, 256, 0, stream>>>(ei, emask, rp, cur, ew);

    // first linear: x (fp32, converted in-kernel) -> embH[0] (+ embeds[0] fp32)
    k_gemm<<<1024, 256, 0, stream>>>(x, W_first, b_first, embH,
                                     out + OFF_EMB, 0, NN);

    for (int l = 0; l < NL; ++l) {
        k_agg<<<(NN / 4) * 8, 256, 0, stream>>>(embH + (size_t)l * NN * 128, bufP, rp, ew, eps, l);
        k_slp<<<1024, 512, 0, stream>>>(bufP,
                                        gin_W + (size_t)(l * 2 + 0) * 128 * 128,
                                        gin_b + (size_t)(l * 2 + 0) * 128,
                                        gin_W + (size_t)(l * 2 + 1) * 128 * 128,
                                        gin_b + (size_t)(l * 2 + 1) * 128,
                                        embH + (size_t)(l + 1) * NN * 128,
                                        out + OFF_EMB + (size_t)(l + 1) * NN * 128);
    }

    k_pool_partial<<<NG * 8, 128, 0, stream>>>(embH, batch, ps_tmp);
    k_final<<<NG, 128, 0, stream>>>(ps_tmp, W1, b1, W2, b2, out);
}

// Round 4
// 918.276 us; speedup vs baseline: 2.0569x; 2.0569x over previous
//
#include <hip/hip_runtime.h>

typedef unsigned int u32;
typedef unsigned short u16;

typedef _Float16 f16x8 __attribute__((ext_vector_type(8)));
typedef _Float16 f16x2 __attribute__((ext_vector_type(2)));
typedef float    f32x4 __attribute__((ext_vector_type(4)));

constexpr int NN = 100000;   // nodes
constexpr int NE = 1600000;  // edges
constexpr int NG = 256;      // graphs
constexpr int DH = 128;      // hidden dim
constexpr int NL = 4;        // GIN layers
constexpr int NTILES = NN / 16;  // 6250

// d_out layout (fp32 elements)
constexpr long long OFF_EMB  = 0;                       // 5*NN*128
constexpr long long OFF_PS   = 64000000LL;              // 256*128
constexpr long long OFF_L1   = OFF_PS  + (long long)NG*DH;
constexpr long long OFF_L1D  = OFF_L1  + (long long)NG*DH;
constexpr long long OFF_L2   = OFF_L1D + (long long)NG*DH;
constexpr long long OFF_SOFT = OFF_L2  + (long long)NG*8;

__device__ __forceinline__ u16 f2h(float f) {
    union { _Float16 h; u16 s; } c; c.h = (_Float16)f; return c.s;
}
__device__ __forceinline__ float h2f(u16 s) {
    union { u16 s; _Float16 h; } c; c.s = s; return (float)c.h;
}

// v_fma_mix-friendly weighted accumulate of a packed half2:
// a0 += w*h[0]; a1 += w*h[1]  (f32 fma, inline f16->f32 operand conversion)
__device__ __forceinline__ void mix2(float& a0, float& a1, float w, u32 v) {
    f16x2 h = __builtin_bit_cast(f16x2, v);
    a0 += w * (float)h[0];
    a1 += w * (float)h[1];
}

union U16x8 { uint4 u; f16x8 h; u16 s[8]; };

// ---------------- CSR build ----------------
__global__ __launch_bounds__(256) void k_hist(const int* __restrict__ ei, int* __restrict__ cnt) {
    int e = blockIdx.x * 256 + threadIdx.x;
    if (e < NE) atomicAdd(&cnt[ei[e]], 1);
}

__global__ __launch_bounds__(256) void k_scan1(const int* __restrict__ cnt,
                                               int* __restrict__ rp, int* __restrict__ bsum) {
    __shared__ int sd[256];
    int t = threadIdx.x;
    int base = blockIdx.x * 1024 + t * 4;
    int v0 = (base + 0 < NN) ? cnt[base + 0] : 0;
    int v1 = (base + 1 < NN) ? cnt[base + 1] : 0;
    int v2 = (base + 2 < NN) ? cnt[base + 2] : 0;
    int v3 = (base + 3 < NN) ? cnt[base + 3] : 0;
    int s = v0 + v1 + v2 + v3;
    sd[t] = s; __syncthreads();
    for (int off = 1; off < 256; off <<= 1) {
        int x = (t >= off) ? sd[t - off] : 0;
        __syncthreads();
        sd[t] += x;
        __syncthreads();
    }
    int e = sd[t] - s;
    if (base + 0 < NN) rp[base + 0] = e; e += v0;
    if (base + 1 < NN) rp[base + 1] = e; e += v1;
    if (base + 2 < NN) rp[base + 2] = e; e += v2;
    if (base + 3 < NN) rp[base + 3] = e;
    if (t == 255) bsum[blockIdx.x] = sd[255];
}

__global__ void k_scan2(int* __restrict__ bsum, int nb) {
    __shared__ int sd[128];
    int t = threadIdx.x;
    int v = (t < nb) ? bsum[t] : 0;
    sd[t] = v; __syncthreads();
    for (int off = 1; off < 128; off <<= 1) {
        int x = (t >= off) ? sd[t - off] : 0;
        __syncthreads();
        sd[t] += x;
        __syncthreads();
    }
    if (t < nb) bsum[t] = sd[t] - v;
}

__global__ __launch_bounds__(256) void k_scan3(int* __restrict__ rp, const int* __restrict__ bsum) {
    int t = threadIdx.x;
    int base = blockIdx.x * 1024 + t * 4;
    int add = bsum[blockIdx.x];
    #pragma unroll
    for (int j = 0; j < 4; ++j)
        if (base + j < NN) rp[base + j] += add;
    if (blockIdx.x == 0 && t == 0) rp[NN] = NE;
}

// scatter (src, w) interleaved: one 8B random store per edge instead of two 4B
// stores to two arrays -> half the dirty-line touches.
__global__ __launch_bounds__(256) void k_scatter(const int* __restrict__ ei,
                                                 const float* __restrict__ mask,
                                                 const int* __restrict__ rp,
                                                 int* __restrict__ cur,
                                                 int2* __restrict__ ew) {
    int e = blockIdx.x * 256 + threadIdx.x;
    if (e >= NE) return;
    int d = ei[e];
    int pos = rp[d] + atomicAdd(&cur[d], 1);
    ew[pos] = make_int2(ei[NE + e], __float_as_int(mask[e]));
}

// ---------------- aggregation: pooled = agg + (1+eps)*h, fp16 in/out ----------------
// One 64-lane wave per node (row-major layout; R2 structure). node/rp/meta are
// wave-uniform -> forced into SGPRs via readfirstlane so edge meta comes off the
// scalar pipe (s_load_dwordx4) and loop control is SALU; only the 8 row gathers
// per batch use the vector memory pipe. Inner math is v_fma_mix-shaped.
__global__ __launch_bounds__(256) void k_agg(const u16* __restrict__ h,
                                             u16* __restrict__ pooled,
                                             const int* __restrict__ rp,
                                             const int2* __restrict__ ew,
                                             const float* __restrict__ eps, int layer) {
    int lane = threadIdx.x & 63;
    int node = (blockIdx.x * 256 + threadIdx.x) >> 6;
    if (node >= NN) return;
    node = __builtin_amdgcn_readfirstlane(node);
    const u32* h32 = (const u32*)h;
    float a0 = 0.f, a1 = 0.f;
    int e0 = __builtin_amdgcn_readfirstlane(rp[node]);
    int e1 = __builtin_amdgcn_readfirstlane(rp[node + 1]);
    int e = e0;
    int ehead = (e0 + 3) & ~3;
    if (ehead > e1) ehead = e1;
    for (; e < ehead; ++e) {
        int2 p = ew[e];
        mix2(a0, a1, __int_as_float(p.y), h32[(size_t)p.x * 64 + lane]);
    }
    for (; e + 8 <= e1; e += 8) {
        uint4 q0 = *(const uint4*)(ew + e);
        uint4 q1 = *(const uint4*)(ew + e + 2);
        uint4 q2 = *(const uint4*)(ew + e + 4);
        uint4 q3 = *(const uint4*)(ew + e + 6);
        u32 v0 = h32[(size_t)(int)q0.x * 64 + lane];
        u32 v1 = h32[(size_t)(int)q0.z * 64 + lane];
        u32 v2 = h32[(size_t)(int)q1.x * 64 + lane];
        u32 v3 = h32[(size_t)(int)q1.z * 64 + lane];
        u32 v4 = h32[(size_t)(int)q2.x * 64 + lane];
        u32 v5 = h32[(size_t)(int)q2.z * 64 + lane];
        u32 v6 = h32[(size_t)(int)q3.x * 64 + lane];
        u32 v7 = h32[(size_t)(int)q3.z * 64 + lane];
        mix2(a0, a1, __int_as_float(q0.y), v0);
        mix2(a0, a1, __int_as_float(q0.w), v1);
        mix2(a0, a1, __int_as_float(q1.y), v2);
        mix2(a0, a1, __int_as_float(q1.w), v3);
        mix2(a0, a1, __int_as_float(q2.y), v4);
        mix2(a0, a1, __int_as_float(q2.w), v5);
        mix2(a0, a1, __int_as_float(q3.y), v6);
        mix2(a0, a1, __int_as_float(q3.w), v7);
    }
    for (; e + 2 <= e1; e += 2) {
        uint4 q0 = *(const uint4*)(ew + e);
        u32 v0 = h32[(size_t)(int)q0.x * 64 + lane];
        u32 v1 = h32[(size_t)(int)q0.z * 64 + lane];
        mix2(a0, a1, __int_as_float(q0.y), v0);
        mix2(a0, a1, __int_as_float(q0.w), v1);
    }
    if (e < e1) {
        int2 p = ew[e];
        mix2(a0, a1, __int_as_float(p.y), h32[(size_t)p.x * 64 + lane]);
    }
    float ep = 1.f + eps[layer];
    mix2(a0, a1, ep, h32[(size_t)node * 64 + lane]);
    u32 o = (u32)f2h(a0) | ((u32)f2h(a1) << 16);
    ((u32*)pooled)[(size_t)node * 64 + lane] = o;
}

// ---- shared W-fragment loader: B[k][n] = W[n][k]; lane holds n=lane&15, k=q*8+j;
// hi/lo split recovers fp32 W precision through fp16 MFMA.
__device__ __forceinline__ void load_wfrags(const float* __restrict__ W,
                                            const float* __restrict__ b,
                                            int sub, int m, int q,
                                            f16x8 (&bhi)[2][4], f16x8 (&blo)[2][4],
                                            float (&bs)[2]) {
    #pragma unroll
    for (int t = 0; t < 2; ++t) {
        int n = sub * 32 + t * 16 + m;
        const float* wr = W + (size_t)n * 128 + q * 8;
        bs[t] = b[n];
        #pragma unroll
        for (int kb = 0; kb < 4; ++kb) {
            float4 f0 = *(const float4*)(wr + kb * 32);
            float4 f1 = *(const float4*)(wr + kb * 32 + 4);
            float f[8] = {f0.x, f0.y, f0.z, f0.w, f1.x, f1.y, f1.z, f1.w};
            f16x8 hi, lo;
            #pragma unroll
            for (int j = 0; j < 8; ++j) {
                _Float16 h = (_Float16)f[j];
                hi[j] = h;
                lo[j] = (_Float16)(f[j] - (float)h);
            }
            bhi[t][kb] = hi;
            blo[t][kb] = lo;
        }
    }
}

// ---------------- GEMM: out[M,128] = A[M,128] @ W^T + b (first layer only) ----
// outf (fp32 embeds) is write-only for us: nontemporal stores keep the 51 MB
// stream from evicting the live fp16 working set out of L3. Same for the
// read-once fp32 x input (nontemporal loads).
__global__ __launch_bounds__(256) void k_gemm(const u16* __restrict__ A,
                                              const float* __restrict__ Af32,
                                              const float* __restrict__ W,
                                              const float* __restrict__ bias,
                                              u16* __restrict__ outh,
                                              float* __restrict__ outf,
                                              int relu, int M) {
    __shared__ float stage[4][16 * 36];
    float* st = stage[threadIdx.x >> 6];
    const int lane = threadIdx.x & 63;
    const int wid = (blockIdx.x * 256 + threadIdx.x) >> 6;
    const int nwaves = (gridDim.x * 256) >> 6;
    const int m = lane & 15, q = lane >> 4;
    const int pair = wid & 3;          // cols [pair*32, pair*32+32)
    const int tile0 = wid >> 2;
    const int tstride = nwaves >> 2;

    f16x8 bhi[2][4], blo[2][4];
    float bs[2];
    load_wfrags(W, bias, pair, m, q, bhi, blo, bs);

    const int rdrow = lane >> 2, rdcg = lane & 3;   // epilogue readback mapping
    const int ntiles = M / 16;
    for (int tile = tile0; tile < ntiles; tile += tstride) {
        int row0 = tile * 16;
        f16x8 af[4];
        if (Af32) {
            const float* ap = Af32 + (size_t)(row0 + m) * 128 + q * 8;
            #pragma unroll
            for (int kb = 0; kb < 4; ++kb) {
                f32x4 f0 = __builtin_nontemporal_load((const f32x4*)(ap + kb * 32));
                f32x4 f1 = __builtin_nontemporal_load((const f32x4*)(ap + kb * 32 + 4));
                f16x8 h;
                h[0] = (_Float16)f0[0]; h[1] = (_Float16)f0[1];
                h[2] = (_Float16)f0[2]; h[3] = (_Float16)f0[3];
                h[4] = (_Float16)f1[0]; h[5] = (_Float16)f1[1];
                h[6] = (_Float16)f1[2]; h[7] = (_Float16)f1[3];
                af[kb] = h;
            }
        } else {
            const uint4* ap = (const uint4*)(A + (size_t)(row0 + m) * 128 + q * 8);
            #pragma unroll
            for (int kb = 0; kb < 4; ++kb) {
                U16x8 u; u.u = ap[kb * 4];
                af[kb] = u.h;
            }
        }
        f32x4 acc[2] = {{0.f, 0.f, 0.f, 0.f}, {0.f, 0.f, 0.f, 0.f}};
        #pragma unroll
        for (int t = 0; t < 2; ++t)
            #pragma unroll
            for (int kb = 0; kb < 4; ++kb) {
                acc[t] = __builtin_amdgcn_mfma_f32_16x16x32_f16(af[kb], bhi[t][kb], acc[t], 0, 0, 0);
                acc[t] = __builtin_amdgcn_mfma_f32_16x16x32_f16(af[kb], blo[t][kb], acc[t], 0, 0, 0);
            }
        // stage to LDS: C/D layout col=lane&15, row=q*4+r (m89/m91)
        #pragma unroll
        for (int t = 0; t < 2; ++t)
            #pragma unroll
            for (int r = 0; r < 4; ++r) {
                float v = acc[t][r] + bs[t];
                if (relu) v = fmaxf(v, 0.f);
                st[(q * 4 + r) * 36 + t * 16 + m] = v;
            }
        // coalesced readback + stores (wave-private region; lgkmcnt ordering)
        f32x4 v0 = *(const f32x4*)&st[rdrow * 36 + rdcg * 8];
        f32x4 v1 = *(const f32x4*)&st[rdrow * 36 + rdcg * 8 + 4];
        size_t gbase = (size_t)(row0 + rdrow) * 128 + pair * 32 + rdcg * 8;
        U16x8 p;
        p.s[0] = f2h(v0[0]); p.s[1] = f2h(v0[1]); p.s[2] = f2h(v0[2]); p.s[3] = f2h(v0[3]);
        p.s[4] = f2h(v1[0]); p.s[5] = f2h(v1[1]); p.s[6] = f2h(v1[2]); p.s[7] = f2h(v1[3]);
        *(uint4*)(outh + gbase) = p.u;
        if (outf) {
            __builtin_nontemporal_store(v0, (f32x4*)(outf + gbase));
            __builtin_nontemporal_store(v1, (f32x4*)(outf + gbase + 4));
        }
    }
}

// ---------------- fused SLP: out = relu(relu(A@W0^T+b0)@W1^T+b1) ----------------
// 8 waves / block. Waves 0-3 (producers) run GEMM1 for a 16-row tile and write
// the fp16 intermediate to a double-buffered LDS tile; waves 4-7 (consumers)
// run GEMM2 out of LDS one tile behind and store fp16+fp32 outputs. One
// __syncthreads per tile; both branches execute exactly nt+1 barriers.
__global__ __launch_bounds__(512) void k_slp(const u16* __restrict__ A,
                                             const float* __restrict__ W0,
                                             const float* __restrict__ b0,
                                             const float* __restrict__ W1,
                                             const float* __restrict__ b1,
                                             u16* __restrict__ outh,
                                             float* __restrict__ outf) {
    __shared__ u16 inter[2][16 * 136];      // 136-half row stride: 16B-aligned rows
    __shared__ float stage[4][16 * 36];
    const int lane = threadIdx.x & 63;
    const int w8 = threadIdx.x >> 6;        // 0..7
    const int m = lane & 15, q = lane >> 4;
    const int sub = w8 & 3;
    const int G = gridDim.x;
    const int nt = (NTILES - (int)blockIdx.x + G - 1) / G;   // G <= NTILES

    if (w8 < 4) {
        // -------- producer: inter = relu(A @ W0^T + b0), fp16 --------
        f16x8 bhi[2][4], blo[2][4];
        float bs[2];
        load_wfrags(W0, b0, sub, m, q, bhi, blo, bs);

        f16x8 afc[4], afn[4];
        {   // prologue load, tile 0
            const uint4* ap = (const uint4*)(A + (size_t)((int)blockIdx.x * 16 + m) * 128 + q * 8);
            #pragma unroll
            for (int kb = 0; kb < 4; ++kb) { U16x8 u; u.u = ap[kb * 4]; afc[kb] = u.h; }
        }
        for (int i = 0; i < nt; ++i) {
            int tn = (int)blockIdx.x + (i + 1) * G;
            if (tn < NTILES) {  // prefetch next tile's A before MFMA on current
                const uint4* ap = (const uint4*)(A + (size_t)(tn * 16 + m) * 128 + q * 8);
                #pragma unroll
                for (int kb = 0; kb < 4; ++kb) { U16x8 u; u.u = ap[kb * 4]; afn[kb] = u.h; }
            }
            f32x4 acc[2] = {{0.f, 0.f, 0.f, 0.f}, {0.f, 0.f, 0.f, 0.f}};
            #pragma unroll
            for (int t = 0; t < 2; ++t)
                #pragma unroll
                for (int kb = 0; kb < 4; ++kb) {
                    acc[t] = __builtin_amdgcn_mfma_f32_16x16x32_f16(afc[kb], bhi[t][kb], acc[t], 0, 0, 0);
                    acc[t] = __builtin_amdgcn_mfma_f32_16x16x32_f16(afc[kb], blo[t][kb], acc[t], 0, 0, 0);
                }
            u16* ib = inter[i & 1];
            #pragma unroll
            for (int t = 0; t < 2; ++t)
                #pragma unroll
                for (int r = 0; r < 4; ++r) {
                    float v = fmaxf(acc[t][r] + bs[t], 0.f);
                    // C/D layout: row=q*4+r, col=sub*32+t*16+m
                    ib[(q * 4 + r) * 136 + sub * 32 + t * 16 + m] = f2h(v);
                }
            __syncthreads();
            #pragma unroll
            for (int kb = 0; kb < 4; ++kb) afc[kb] = afn[kb];
        }
        __syncthreads();   // matches consumer's final in-loop barrier
    } else {
        // -------- consumer: out = relu(inter @ W1^T + b1) --------
        f16x8 bhi[2][4], blo[2][4];
        float bs[2];
        load_wfrags(W1, b1, sub, m, q, bhi, blo, bs);
        float* st = stage[sub];
        const int rdrow = lane >> 2, rdcg = lane & 3;

        __syncthreads();   // matches producer's i=0 barrier: tile 0 now visible
        for (int i = 0; i < nt; ++i) {
            int tile = (int)blockIdx.x + i * G;
            const u16* ib = inter[i & 1];
            f16x8 af[4];
            #pragma unroll
            for (int kb = 0; kb < 4; ++kb)   // A row = lane&15, k = q*8 + kb*32 + j
                af[kb] = *(const f16x8*)&ib[m * 136 + q * 8 + kb * 32];
            f32x4 acc[2] = {{0.f, 0.f, 0.f, 0.f}, {0.f, 0.f, 0.f, 0.f}};
            #pragma unroll
            for (int t = 0; t < 2; ++t)
                #pragma unroll
                for (int kb = 0; kb < 4; ++kb) {
                    acc[t] = __builtin_amdgcn_mfma_f32_16x16x32_f16(af[kb], bhi[t][kb], acc[t], 0, 0, 0);
                    acc[t] = __builtin_amdgcn_mfma_f32_16x16x32_f16(af[kb], blo[t][kb], acc[t], 0, 0, 0);
                }
            #pragma unroll
            for (int t = 0; t < 2; ++t)
                #pragma unroll
                for (int r = 0; r < 4; ++r) {
                    float v = fmaxf(acc[t][r] + bs[t], 0.f);
                    st[(q * 4 + r) * 36 + t * 16 + m] = v;
                }
            f32x4 v0 = *(const f32x4*)&st[rdrow * 36 + rdcg * 8];
            f32x4 v1 = *(const f32x4*)&st[rdrow * 36 + rdcg * 8 + 4];
            size_t gbase = (size_t)(tile * 16 + rdrow) * 128 + sub * 32 + rdcg * 8;
            U16x8 p;
            p.s[0] = f2h(v0[0]); p.s[1] = f2h(v0[1]); p.s[2] = f2h(v0[2]); p.s[3] = f2h(v0[3]);
            p.s[4] = f2h(v1[0]); p.s[5] = f2h(v1[1]); p.s[6] = f2h(v1[2]); p.s[7] = f2h(v1[3]);
            *(uint4*)(outh + gbase) = p.u;
            __builtin_nontemporal_store(v0, (f32x4*)(outf + gbase));
            __builtin_nontemporal_store(v1, (f32x4*)(outf + gbase + 4));
            __syncthreads();
        }
    }
}

// ---------------- graph pooling from fp16 embeds ----------------
__device__ __forceinline__ int lbound(const int* b, int n, int v) {
    int lo = 0, hi = n;
    while (lo < hi) { int mid = (lo + hi) >> 1; if (b[mid] < v) lo = mid + 1; else hi = mid; }
    return lo;
}

// u32-vectorized: each lane sums 2 columns; 16 node-stripes per graph
// (8 blocks x 2 waves).
__global__ __launch_bounds__(128) void k_pool_partial(const u16* __restrict__ embH,
                                                      const int* __restrict__ batch,
                                                      float* __restrict__ ps_tmp) {
    int g = blockIdx.x >> 3, s8 = blockIdx.x & 7;
    int w = threadIdx.x >> 6;          // 0..1
    int lane = threadIdx.x & 63;
    int s = s8 * 2 + w;                // 16 stripes
    int lo = lbound(batch, NN, g);
    int hi = lbound(batch, NN, g + 1);
    const u32* h32 = (const u32*)embH;
    float a0 = 0.f, a1 = 0.f;
    for (int n = lo + s; n < hi; n += 16) {
        size_t base = (size_t)n * 64 + lane;
        #pragma unroll
        for (int e = 0; e < 5; ++e) {
            u32 v = h32[(size_t)e * NN * 64 + base];
            f16x2 hh = __builtin_bit_cast(f16x2, v);
            a0 += (float)hh[0];
            a1 += (float)hh[1];
        }
    }
    atomicAdd(&ps_tmp[g * 128 + lane * 2], a0);
    atomicAdd(&ps_tmp[g * 128 + lane * 2 + 1], a1);
}

// ---------------- head: pooled_sum -> lin1 -> lin2 -> softmax ----------------
__global__ __launch_bounds__(128) void k_final(const float* __restrict__ ps_tmp,
                                               const float* __restrict__ W1, const float* __restrict__ b1,
                                               const float* __restrict__ W2, const float* __restrict__ b2,
                                               float* __restrict__ out) {
    int g = blockIdx.x, t = threadIdx.x;
    __shared__ float ps[128], l1[128], l2[8];
    float v = ps_tmp[g * 128 + t];
    ps[t] = v;
    out[OFF_PS + (size_t)g * 128 + t] = v;
    __syncthreads();
    float a = b1[t];
    #pragma unroll 8
    for (int k = 0; k < 128; ++k) a += ps[k] * W1[t * 128 + k];
    a = fmaxf(a, 0.f);
    l1[t] = a;
    out[OFF_L1  + (size_t)g * 128 + t] = a;
    out[OFF_L1D + (size_t)g * 128 + t] = a;
    __syncthreads();
    if (t < 8) {
        float a2 = b2[t];
        #pragma unroll 8
        for (int k = 0; k < 128; ++k) a2 += l1[k] * W2[t * 128 + k];
        l2[t] = a2;
        out[OFF_L2 + (size_t)g * 8 + t] = a2;
    }
    __syncthreads();
    if (t == 0) {
        float mx = l2[0];
        for (int j = 1; j < 8; ++j) mx = fmaxf(mx, l2[j]);
        float e[8], s = 0.f;
        for (int j = 0; j < 8; ++j) { e[j] = __expf(l2[j] - mx); s += e[j]; }
        float inv = 1.f / s;
        for (int j = 0; j < 8; ++j) out[OFF_SOFT + (size_t)g * 8 + j] = e[j] * inv;
    }
}

extern "C" void kernel_launch(void* const* d_in, const int* in_sizes, int n_in,
                              void* d_out, int out_size, void* d_ws, size_t ws_size,
                              hipStream_t stream) {
    const float* x       = (const float*)d_in[0];
    const int*   ei      = (const int*)d_in[1];
    const float* emask   = (const float*)d_in[2];
    const int*   batch   = (const int*)d_in[3];
    const float* eps     = (const float*)d_in[4];
    const float* W_first = (const float*)d_in[5];
    const float* b_first = (const float*)d_in[6];
    const float* gin_W   = (const float*)d_in[7];
    const float* gin_b   = (const float*)d_in[8];
    const float* W1      = (const float*)d_in[9];
    const float* b1      = (const float*)d_in[10];
    const float* W2      = (const float*)d_in[11];
    const float* b2      = (const float*)d_in[12];
    float* out = (float*)d_out;

    char* ws = (char*)d_ws;
    const size_t HB = (size_t)NN * 128 * 2;       // 25.6 MB per fp16 node buffer
    u16* embH = (u16*)(ws);                       // 5 contiguous embed buffers
    size_t o = 5 * HB;
    u16* bufP = (u16*)(ws + o); o += HB;          // agg output
    int* cnt  = (int*)(ws + o); o += 400000;
    int* cur  = (int*)(ws + o); o += 400000;
    float* ps_tmp = (float*)(ws + o); o += (size_t)NG * DH * 4;
    int* rp   = (int*)(ws + o); o += 400064;      // NN+1 ints, padded
    int* bsum = (int*)(ws + o); o += 512;
    int2* ew  = (int2*)(ws + o); o += (size_t)NE * 8;  // interleaved (src, w)

    // one memset covers cnt + cur + ps_tmp (adjacent)
    hipMemsetAsync(cnt, 0, 400000 + 400000 + (size_t)NG * DH * 4, stream);

    // CSR build
    k_hist<<<NE / 256, 256, 0, stream>>>(ei, cnt);
    k_scan1<<<98, 256, 0, stream>>>(cnt, rp, bsum);
    k_scan2<<<1, 128, 0, stream>>>(bsum, 98);
    k_scan3<<<98, 256, 0, stream>>>(rp, bsum);
    k_scatter<<<NE / 256, 256, 0, stream>>>(ei, emask, rp, cur, ew);

    // first linear: x (fp32, converted in-kernel) -> embH[0] (+ embeds[0] fp32)
    k_gemm<<<1024, 256, 0, stream>>>(nullptr, x, W_first, b_first, embH,
                                     out + OFF_EMB, 0, NN);

    for (int l = 0; l < NL; ++l) {
        k_agg<<<NN / 4, 256, 0, stream>>>(embH + (size_t)l * NN * 128, bufP, rp, ew, eps, l);
        k_slp<<<1024, 512, 0, stream>>>(bufP,
                                        gin_W + (size_t)(l * 2 + 0) * 128 * 128,
                                        gin_b + (size_t)(l * 2 + 0) * 128,
                                        gin_W + (size_t)(l * 2 + 1) * 128 * 128,
                                        gin_b + (size_t)(l * 2 + 1) * 128,
                                        embH + (size_t)(l + 1) * NN * 128,
                                        out + OFF_EMB + (size_t)(l + 1) * NN * 128);
    }

    k_pool_partial<<<NG * 8, 128, 0, stream>>>(embH, batch, ps_tmp);
    k_final<<<NG, 128, 0, stream>>>(ps_tmp, W1, b1, W2, b2, out);
}